// Round 7
// baseline (3084.231 us; speedup 1.0000x reference)
//
#include <hip/hip_runtime.h>
#include <stdint.h>

// CfC RNN: B=256, T=1024, I=64, U=256, O=64, BB=128. All I/O float32.
//
// Round 7: dual-sequence WGs. r6's kernel (1308 us) is bound by the serial
// bb->g->ff->h cycle: MFMA pipe ~1242 cyc/CU/step idles during VALU/trans
// epilogues and vice versa. Fix: 8 WGs x 32 rows = TWO independent 16-row
// recurrences per WG, phases interleaved (bbA,bbB,gA,gB | ffA,ffB,hA,hB) so
// one sequence's MFMAs overlap the other's epilogues. Weights shared between
// sequences (no extra VGPR for the big arrays). Everything else = r6:
//  - (u,u+16) h pairing, single-pkrtz h pack, XOR-swizzled h LDS region
//  - delay-slot Hbuf stores, Px x-path hoist, one-rcp h epilogue
//  - bb now 4 indep 2-MFMA chains (shorter dep chain)
// Tiers: ws>=192MiB: px+cfc_dual+ro<new>; >=128MiB: r5-style cfc_mfma<false>
// + ro<old>; else dot2 fallback.
#define B_ 256
#define T_ 1024
#define I_ 64
#define U_ 256
#define O_ 64
#define BB_ 128

typedef unsigned int u32;
typedef unsigned short u16;
typedef _Float16 half2_t __attribute__((ext_vector_type(2)));
typedef _Float16 f16x8 __attribute__((ext_vector_type(8)));
typedef float f32x4 __attribute__((ext_vector_type(4)));

#if defined(__has_builtin)
#if __has_builtin(__builtin_amdgcn_fdot2)
#define USE_DOT2 1
#else
#define USE_DOT2 0
#endif
#else
#define USE_DOT2 0
#endif

static __device__ __forceinline__ u32 packpair(float a, float b) {
  half2_t h; h.x = (_Float16)a; h.y = (_Float16)b;
  return __builtin_bit_cast(u32, h);
}
#if defined(__has_builtin) && __has_builtin(__builtin_amdgcn_cvt_pkrtz)
static __device__ __forceinline__ u32 pkrtz(float a, float b) {
  return __builtin_bit_cast(u32, __builtin_amdgcn_cvt_pkrtz(a, b));
}
#else
static __device__ __forceinline__ u32 pkrtz(float a, float b) {
  return packpair(a, b);
}
#endif
static __device__ __forceinline__ float unpack_lo(u32 u) {
  half2_t h = __builtin_bit_cast(half2_t, u); return (float)h.x;
}
static __device__ __forceinline__ float unpack_hi(u32 u) {
  half2_t h = __builtin_bit_cast(half2_t, u); return (float)h.y;
}
static __device__ __forceinline__ float dot2acc(u32 w, u32 z, float acc) {
#if USE_DOT2
  return __builtin_amdgcn_fdot2(__builtin_bit_cast(half2_t, w),
                                __builtin_bit_cast(half2_t, z), acc, false);
#else
  half2_t hw = __builtin_bit_cast(half2_t, w);
  half2_t hz = __builtin_bit_cast(half2_t, z);
  acc += (float)hw.x * (float)hz.x;
  acc += (float)hw.y * (float)hz.y;
  return acc;
#endif
}

// DPP cross-lane moves (VALU pipe; no LDS). Palindromic controls only.
template <int CTRL>
static __device__ __forceinline__ float dpp_mov_f(float v) {
  return __builtin_bit_cast(float, __builtin_amdgcn_update_dpp(
      0, __builtin_bit_cast(int, v), CTRL, 0xF, 0xF, true));
}
#define DPP_XOR1 0xB1
#define DPP_XOR2 0x4E
#define DPP_HMIR 0x141
#define DPP_MIRR 0x140

static __device__ __forceinline__ float fast_tanh(float x) {
  return 1.0f - 2.0f / (1.0f + __expf(2.0f * x));
}
static __device__ __forceinline__ float fast_sigmoid(float x) {
  return 1.0f / (1.0f + __expf(-x));
}

static __device__ __forceinline__ float rcpf(float x) {
#if defined(__has_builtin) && __has_builtin(__builtin_amdgcn_rcpf)
  return __builtin_amdgcn_rcpf(x);
#else
  return 1.0f / x;
#endif
}
static __device__ __forceinline__ float exp2fast(float x) {
#if defined(__has_builtin) && __has_builtin(__builtin_amdgcn_exp2f)
  return __builtin_amdgcn_exp2f(x);
#else
  return exp2f(x);
#endif
}

static __device__ __forceinline__ f32x4 mfma16(uint4 a, uint4 b, f32x4 c) {
  return __builtin_amdgcn_mfma_f32_16x16x32_f16(
      __builtin_bit_cast(f16x8, a), __builtin_bit_cast(f16x8, b), c, 0, 0, 0);
}

#define LOG2E 1.44269504f

// ====================== Px pre-GEMM (x-path hoist) ========================
// Px[rr, t, w, lane] = D-frag of (x[rr*16..+15, t, :] @ W_bb[0:64,:] + b_bb)
// for n-tile w. Packed f16 pairs (acc0,acc1),(acc2,acc3) -> uint2.
__global__ __launch_bounds__(512, 2)
void px_kernel(const float* __restrict__ x,
               const float* __restrict__ W_bb, const float* __restrict__ b_bb,
               u32* __restrict__ Px)
{
  const int tid = threadIdx.x;
  const int l   = tid & 63;
  const int w   = tid >> 6;        // n-tile 0..7
  const int c16 = l & 15;
  const int q4  = l >> 4;
  const int rr  = blockIdx.x;      // row-group 0..15
  const int t0  = blockIdx.y * 64; // 64 steps per WG

  uint4 wpx[2];
  {
    const int colb = w * 16 + c16;
#pragma unroll
    for (int c = 0; c < 2; ++c) {
      u32 qv[4];
#pragma unroll
      for (int q = 0; q < 4; ++q) {
        const int k0 = c * 32 + q4 * 8 + 2 * q;
        qv[q] = packpair(W_bb[(size_t)k0 * BB_ + colb],
                         W_bb[(size_t)(k0 + 1) * BB_ + colb]);
      }
      wpx[c] = make_uint4(qv[0], qv[1], qv[2], qv[3]);
    }
  }
  const float bc = b_bb[w * 16 + c16];

  const float* xr = x + ((size_t)(rr * 16 + c16)) * T_ * I_ + q4 * 8;
  uint2* __restrict__ pxo =
      (uint2*)Px + ((size_t)rr * T_ + t0) * 512 + w * 64 + l;

  for (int i = 0; i < 64; ++i) {
    const int t = t0 + i;
    const float* xt = xr + (size_t)t * I_;
    float4 v0 = *(const float4*)(xt);
    float4 v1 = *(const float4*)(xt + 4);
    float4 v2 = *(const float4*)(xt + 32);
    float4 v3 = *(const float4*)(xt + 36);
    uint4 a0 = make_uint4(pkrtz(v0.x, v0.y), pkrtz(v0.z, v0.w),
                          pkrtz(v1.x, v1.y), pkrtz(v1.z, v1.w));
    uint4 a1 = make_uint4(pkrtz(v2.x, v2.y), pkrtz(v2.z, v2.w),
                          pkrtz(v3.x, v3.y), pkrtz(v3.z, v3.w));
    f32x4 acc = {bc, bc, bc, bc};
    acc = mfma16(a0, wpx[0], acc);
    acc = mfma16(a1, wpx[1], acc);
    uint2 o;
    o.x = pkrtz(acc[0], acc[1]);
    o.y = pkrtz(acc[2], acc[3]);
    pxo[(size_t)i * 512] = o;
  }
}

// ================== dual-sequence MFMA main kernel (round 7) ==============
__global__ __launch_bounds__(512, 2)
void cfc_dual(const float* __restrict__ W_bb,
              const float* __restrict__ W_ff1, const float* __restrict__ b_ff1,
              const float* __restrict__ W_ff2, const float* __restrict__ b_ff2,
              const float* __restrict__ W_ta,  const float* __restrict__ b_ta,
              const float* __restrict__ W_tb,  const float* __restrict__ b_tb,
              float* __restrict__ out, u32* __restrict__ Hbuf,
              const u32* __restrict__ Px)
{
  // Per sequence: h A-frags [8 chunks][64 lanes][uint4] ((u,u+16) pairing,
  // XOR block swizzle LB^((LB>>4)&3)); g A-frags [4 chunks][64 lanes][uint4].
  __shared__ __align__(16) u32 s_zA[2048];
  __shared__ __align__(16) u32 s_zB[2048];
  __shared__ __align__(16) u32 s_gA[1024];
  __shared__ __align__(16) u32 s_gB[1024];

  const int tid = threadIdx.x;
  const int l   = tid & 63;
  const int w   = tid >> 6;        // wave 0..7
  const int c16 = l & 15;
  const int q4  = l >> 4;
  const int odd = l & 1;
  const int rr  = blockIdx.x;      // 0..7
  const int row0A = rr * 32;
  const int row0B = rr * 32 + 16;
  const int lx  = l ^ (l >> 4);    // swizzled h-region read lane

  // ---- bb weights (shared): 8 h-chunks, (u,u+16) pairing ----
  uint4 wbb[8];
  {
    const int colb = w * 16 + c16;
#pragma unroll
    for (int c = 0; c < 8; ++c) {
      u32 qv[4];
#pragma unroll
      for (int q = 0; q < 4; ++q) {
        const int ulo = 32 * c + 4 * q4 + q;
        qv[q] = packpair(W_bb[(size_t)(64 + ulo) * BB_ + colb],
                         W_bb[(size_t)(80 + ulo) * BB_ + colb]);
      }
      wbb[c] = make_uint4(qv[0], qv[1], qv[2], qv[3]);
    }
  }
  // ---- ff weights (shared): wave w owns units w*32..+31, 3 mats ----
  uint4 wff[3][2][4];
#pragma unroll
  for (int ut = 0; ut < 2; ++ut) {
    const int u = w * 32 + ut * 16 + c16;
#pragma unroll
    for (int c = 0; c < 4; ++c) {
      u32 qa[4], qb[4], qc[4];
#pragma unroll
      for (int q = 0; q < 4; ++q) {
        const int k0 = c * 32 + q4 * 8 + 2 * q;
        const size_t i0 = (size_t)k0 * U_ + u, i1 = i0 + U_;
        qa[q] = packpair(W_ff1[i0], W_ff1[i1]);
        qb[q] = packpair(W_ff2[i0], W_ff2[i1]);
        qc[q] = packpair(W_ta[i0] + W_tb[i0], W_ta[i1] + W_tb[i1]);
      }
      wff[0][ut][c] = make_uint4(qa[0], qa[1], qa[2], qa[3]);
      wff[1][ut][c] = make_uint4(qb[0], qb[1], qb[2], qb[3]);
      wff[2][ut][c] = make_uint4(qc[0], qc[1], qc[2], qc[3]);
    }
  }

  // ---- biases (pre-scaled; b_bb folded into Px) ----
  float b1s[2], b2s[2], btn[2];
#pragma unroll
  for (int ut = 0; ut < 2; ++ut) {
    const int u = w * 32 + ut * 16 + c16;
    b1s[ut] = b_ff1[u] * (2.0f * LOG2E);
    b2s[ut] = b_ff2[u] * (2.0f * LOG2E);
    btn[ut] = -(b_ta[u] + b_tb[u]) * LOG2E;
  }

  // ---- Px streams: row-groups 2rr (A) and 2rr+1 (B) ----
  const uint2* pxpA = (const uint2*)Px + (size_t)(2 * rr) * T_ * 512 + w * 64 + l;
  const uint2* pxpB = pxpA + (size_t)T_ * 512;

  // ---- g staging write addresses (old pairing, DPP XOR1) ----
  const int pg = w * 8 + (c16 >> 1);
  const int gw0 = ((pg >> 4) * 64 + 16 * ((pg >> 2) & 3)) * 4 + (pg & 3)
                  + 16 * q4 + (odd ? 8 : 0);

  // ---- h staging write addresses, (u,u+16) pairing + XOR swizzle ----
  int zws_[4];
#pragma unroll
  for (int r = 0; r < 4; ++r) {
    const int lane_cons = 4 * q4 + r + 16 * (c16 >> 2);
    const int LB = w * 64 + lane_cons;
    const int SB = LB ^ (c16 >> 2);
    zws_[r] = SB * 4 + (c16 & 3);
  }
  // ---- Hbuf pointers: word pu = w*16+c16 holds units (32w+c16, +16) ----
  u32 *hpA_[4], *hpB_[4];
#pragma unroll
  for (int r = 0; r < 4; ++r) {
    hpA_[r] = Hbuf + (size_t)(row0A + 4 * q4 + r) * T_ * 128 + (w * 16 + c16);
    hpB_[r] = Hbuf + (size_t)(row0B + 4 * q4 + r) * T_ * 128 + (w * 16 + c16);
  }

  // ---- prologue: h = 0 both sequences; load Px_0 ----
  reinterpret_cast<uint4*>(s_zA)[tid] = make_uint4(0u, 0u, 0u, 0u);
  reinterpret_cast<uint4*>(s_zB)[tid] = make_uint4(0u, 0u, 0u, 0u);
  uint2 pxcA = pxpA[0];
  uint2 pxcB = pxpB[0];
  __syncthreads();

  const uint4* zA = (const uint4*)s_zA;
  const uint4* zB = (const uint4*)s_zB;
  const uint4* gA4 = (const uint4*)s_gA;
  const uint4* gB4 = (const uint4*)s_gB;

  u32 hA0 = 0, hA1 = 0, hA2 = 0, hA3 = 0;
  u32 hB0 = 0, hB1 = 0, hB2 = 0, hB3 = 0;

  for (int t = 0; t < T_; ++t) {
    uint2 pxnA, pxnB;
    const bool more = (t + 1 < T_);
    if (more) {
      pxnA = pxpA[(size_t)(t + 1) * 512];
      pxnB = pxpB[(size_t)(t + 1) * 512];
    }

    // ===== bb A: G = Px + H @ W_bb[64:,:]  (4 indep 2-MFMA chains) =====
    f32x4 a0 = {unpack_lo(pxcA.x), unpack_hi(pxcA.x),
                unpack_lo(pxcA.y), unpack_hi(pxcA.y)};
    f32x4 a1 = {0.f, 0.f, 0.f, 0.f};
    f32x4 a2 = {0.f, 0.f, 0.f, 0.f};
    f32x4 a3 = {0.f, 0.f, 0.f, 0.f};
    a0 = mfma16(zA[0 * 64 + lx], wbb[0], a0);
    a1 = mfma16(zA[1 * 64 + lx], wbb[1], a1);
    a2 = mfma16(zA[2 * 64 + lx], wbb[2], a2);
    a3 = mfma16(zA[3 * 64 + lx], wbb[3], a3);
    a0 = mfma16(zA[4 * 64 + lx], wbb[4], a0);
    a1 = mfma16(zA[5 * 64 + lx], wbb[5], a1);
    a2 = mfma16(zA[6 * 64 + lx], wbb[6], a2);
    a3 = mfma16(zA[7 * 64 + lx], wbb[7], a3);
    const f32x4 abA = (a0 + a1) + (a2 + a3);

    // ===== bb B =====
    f32x4 c0 = {unpack_lo(pxcB.x), unpack_hi(pxcB.x),
                unpack_lo(pxcB.y), unpack_hi(pxcB.y)};
    f32x4 c1 = {0.f, 0.f, 0.f, 0.f};
    f32x4 c2 = {0.f, 0.f, 0.f, 0.f};
    f32x4 c3 = {0.f, 0.f, 0.f, 0.f};
    c0 = mfma16(zB[0 * 64 + lx], wbb[0], c0);
    c1 = mfma16(zB[1 * 64 + lx], wbb[1], c1);
    c2 = mfma16(zB[2 * 64 + lx], wbb[2], c2);
    c3 = mfma16(zB[3 * 64 + lx], wbb[3], c3);
    c0 = mfma16(zB[4 * 64 + lx], wbb[4], c0);
    c1 = mfma16(zB[5 * 64 + lx], wbb[5], c1);
    c2 = mfma16(zB[6 * 64 + lx], wbb[6], c2);
    c3 = mfma16(zB[7 * 64 + lx], wbb[7], c3);
    const f32x4 abB = (c0 + c1) + (c2 + c3);

    // ===== g epilogues (A overlaps bb B's pipe time) =====
    {
      u32 gq[4];
#pragma unroll
      for (int r = 0; r < 4; ++r) {
        const float a  = abA[r] * (1.332f * LOG2E);
        const float rv = rcpf(exp2fast(a) + 1.0f);
        const float g  = __builtin_fmaf(rv, -3.4318f, 1.7159f);
        const float gp = dpp_mov_f<DPP_XOR1>(g);
        gq[r] = odd ? pkrtz(gp, g) : pkrtz(g, gp);
      }
      s_gA[gw0]     = odd ? gq[2] : gq[0];
      s_gA[gw0 + 4] = odd ? gq[3] : gq[1];
    }
    {
      u32 gq[4];
#pragma unroll
      for (int r = 0; r < 4; ++r) {
        const float a  = abB[r] * (1.332f * LOG2E);
        const float rv = rcpf(exp2fast(a) + 1.0f);
        const float g  = __builtin_fmaf(rv, -3.4318f, 1.7159f);
        const float gp = dpp_mov_f<DPP_XOR1>(g);
        gq[r] = odd ? pkrtz(gp, g) : pkrtz(g, gp);
      }
      s_gB[gw0]     = odd ? gq[2] : gq[0];
      s_gB[gw0 + 4] = odd ? gq[3] : gq[1];
    }
    __syncthreads();

    // delay-slot Hbuf stores for step t-1 (drained at end barrier)
    if (t) {
      const size_t o = (size_t)(t - 1) * 128;
      hpA_[0][o] = hA0; hpA_[1][o] = hA1; hpA_[2][o] = hA2; hpA_[3][o] = hA3;
      hpB_[0][o] = hB0; hpB_[1][o] = hB1; hpB_[2][o] = hB2; hpB_[3][o] = hB3;
    }

    // ===== ff A =====
    f32x4 afA[3][2];
#pragma unroll
    for (int mt = 0; mt < 3; ++mt)
#pragma unroll
      for (int ut = 0; ut < 2; ++ut)
        afA[mt][ut] = (f32x4){0.f, 0.f, 0.f, 0.f};
#pragma unroll
    for (int c = 0; c < 4; ++c) {
      const uint4 ga = gA4[c * 64 + l];
#pragma unroll
      for (int mt = 0; mt < 3; ++mt)
#pragma unroll
        for (int ut = 0; ut < 2; ++ut)
          afA[mt][ut] = mfma16(ga, wff[mt][ut][c], afA[mt][ut]);
    }
    // ===== ff B =====
    f32x4 afB[3][2];
#pragma unroll
    for (int mt = 0; mt < 3; ++mt)
#pragma unroll
      for (int ut = 0; ut < 2; ++ut)
        afB[mt][ut] = (f32x4){0.f, 0.f, 0.f, 0.f};
#pragma unroll
    for (int c = 0; c < 4; ++c) {
      const uint4 ga = gB4[c * 64 + l];
#pragma unroll
      for (int mt = 0; mt < 3; ++mt)
#pragma unroll
        for (int ut = 0; ut < 2; ++ut)
          afB[mt][ut] = mfma16(ga, wff[mt][ut][c], afB[mt][ut]);
    }

    // ===== h epilogue A (overlaps ff B's pipe time) =====
#pragma unroll
    for (int r = 0; r < 4; ++r) {
      float h01[2];
#pragma unroll
      for (int ut = 0; ut < 2; ++ut) {
        const float E1 = exp2fast(__builtin_fmaf(afA[0][ut][r], 2.0f * LOG2E, b1s[ut]));
        const float E2 = exp2fast(__builtin_fmaf(afA[1][ut][r], 2.0f * LOG2E, b2s[ut]));
        const float E3 = exp2fast(__builtin_fmaf(afA[2][ut][r], -LOG2E, btn[ut]));
        const float p2 = E2 + 1.0f, p3 = E3 + 1.0f;
        const float qq = p2 * p3;
        const float D  = __builtin_fmaf(E1, qq, qq);
        const float R  = rcpf(D);
        const float u2 = (E2 - E1) - qq;
        h01[ut] = __builtin_fmaf(R + R, u2, 1.0f);
      }
      const u32 pkv = pkrtz(h01[0], h01[1]);
      s_zA[zws_[r]] = pkv;
      if (r == 0) hA0 = pkv; else if (r == 1) hA1 = pkv;
      else if (r == 2) hA2 = pkv; else hA3 = pkv;
    }
    // ===== h epilogue B =====
#pragma unroll
    for (int r = 0; r < 4; ++r) {
      float h01[2];
#pragma unroll
      for (int ut = 0; ut < 2; ++ut) {
        const float E1 = exp2fast(__builtin_fmaf(afB[0][ut][r], 2.0f * LOG2E, b1s[ut]));
        const float E2 = exp2fast(__builtin_fmaf(afB[1][ut][r], 2.0f * LOG2E, b2s[ut]));
        const float E3 = exp2fast(__builtin_fmaf(afB[2][ut][r], -LOG2E, btn[ut]));
        const float p2 = E2 + 1.0f, p3 = E3 + 1.0f;
        const float qq = p2 * p3;
        const float D  = __builtin_fmaf(E1, qq, qq);
        const float R  = rcpf(D);
        const float u2 = (E2 - E1) - qq;
        h01[ut] = __builtin_fmaf(R + R, u2, 1.0f);
      }
      const u32 pkv = pkrtz(h01[0], h01[1]);
      s_zB[zws_[r]] = pkv;
      if (r == 0) hB0 = pkv; else if (r == 1) hB1 = pkv;
      else if (r == 2) hB2 = pkv; else hB3 = pkv;
    }
    pxcA = pxnA;
    pxcB = pxnB;
    __syncthreads();
  }

  // final step's Hbuf stores
  {
    const size_t o = (size_t)(T_ - 1) * 128;
    hpA_[0][o] = hA0; hpA_[1][o] = hA1; hpA_[2][o] = hA2; hpA_[3][o] = hA3;
    hpB_[0][o] = hB0; hpB_[1][o] = hB1; hpB_[2][o] = hB2; hpB_[3][o] = hB3;
  }

  // ---- h_last tails ((u,u+16) convention) ----
  {
    const int c  = tid >> 6;
    const int tl = tid & 63;
    const int tlx = tl ^ (tl >> 4);
    const int ub  = 32 * c + 4 * (tl >> 4);
    {
      const uint4 hv = zA[c * 64 + tlx];
      float* tail = out + (size_t)B_ * T_ * O_ + (size_t)(row0A + (tl & 15)) * 256;
#pragma unroll
      for (int q = 0; q < 4; ++q) {
        const u32 hp = (q == 0) ? hv.x : (q == 1) ? hv.y : (q == 2) ? hv.z : hv.w;
        tail[ub + q]      = unpack_lo(hp);
        tail[ub + q + 16] = unpack_hi(hp);
      }
    }
    {
      const uint4 hv = zB[c * 64 + tlx];
      float* tail = out + (size_t)B_ * T_ * O_ + (size_t)(row0B + (tl & 15)) * 256;
#pragma unroll
      for (int q = 0; q < 4; ++q) {
        const u32 hp = (q == 0) ? hv.x : (q == 1) ? hv.y : (q == 2) ? hv.z : hv.w;
        tail[ub + q]      = unpack_lo(hp);
        tail[ub + q + 16] = unpack_hi(hp);
      }
    }
  }
}

// ================= r5 kernel kept for the mid-ws tier (old pairing) =======
template <bool PX>
__global__ __launch_bounds__(512, 2)
void cfc_mfma(const float* __restrict__ x,
              const float* __restrict__ W_bb, const float* __restrict__ b_bb,
              const float* __restrict__ W_ff1, const float* __restrict__ b_ff1,
              const float* __restrict__ W_ff2, const float* __restrict__ b_ff2,
              const float* __restrict__ W_ta,  const float* __restrict__ b_ta,
              const float* __restrict__ W_tb,  const float* __restrict__ b_tb,
              float* __restrict__ out, u32* __restrict__ Hbuf,
              const u32* __restrict__ Px)
{
  __shared__ __align__(16) u32 s_z[2560];
  __shared__ __align__(16) u32 s_g[1024];

  const int tid = threadIdx.x;
  const int l   = tid & 63;
  const int w   = tid >> 6;
  const int c16 = l & 15;
  const int q4  = l >> 4;
  const int odd = l & 1;
  const int rr  = blockIdx.x;
  const int row0 = rr * 16;

  const int NBB = PX ? 8 : 10;
  const int KOFF = PX ? 64 : 0;
  uint4 wbb[10];
  {
    const int colb = w * 16 + c16;
    for (int c = 0; c < NBB; ++c) {
      u32 qv[4];
#pragma unroll
      for (int q = 0; q < 4; ++q) {
        const int k0 = KOFF + c * 32 + q4 * 8 + 2 * q;
        qv[q] = packpair(W_bb[(size_t)k0 * BB_ + colb],
                         W_bb[(size_t)(k0 + 1) * BB_ + colb]);
      }
      wbb[c] = make_uint4(qv[0], qv[1], qv[2], qv[3]);
    }
  }
  uint4 wff[3][2][4];
#pragma unroll
  for (int ut = 0; ut < 2; ++ut) {
    const int u = w * 32 + ut * 16 + c16;
#pragma unroll
    for (int c = 0; c < 4; ++c) {
      u32 qa[4], qb[4], qc[4];
#pragma unroll
      for (int q = 0; q < 4; ++q) {
        const int k0 = c * 32 + q4 * 8 + 2 * q;
        const size_t i0 = (size_t)k0 * U_ + u, i1 = i0 + U_;
        qa[q] = packpair(W_ff1[i0], W_ff1[i1]);
        qb[q] = packpair(W_ff2[i0], W_ff2[i1]);
        qc[q] = packpair(W_ta[i0] + W_tb[i0], W_ta[i1] + W_tb[i1]);
      }
      wff[0][ut][c] = make_uint4(qa[0], qa[1], qa[2], qa[3]);
      wff[1][ut][c] = make_uint4(qb[0], qb[1], qb[2], qb[3]);
      wff[2][ut][c] = make_uint4(qc[0], qc[1], qc[2], qc[3]);
    }
  }

  const float bgs = PX ? 0.f : b_bb[w * 16 + c16] * (1.332f * LOG2E);
  float b1s[2], b2s[2], btn[2];
#pragma unroll
  for (int ut = 0; ut < 2; ++ut) {
    const int u = w * 32 + ut * 16 + c16;
    b1s[ut] = b_ff1[u] * (2.0f * LOG2E);
    b2s[ut] = b_ff2[u] * (2.0f * LOG2E);
    btn[ut] = -(b_ta[u] + b_tb[u]) * LOG2E;
  }

  const int mx = tid >> 5, px_ = tid & 31;
  const float* xptr = x + (size_t)(row0 + mx) * T_ * I_ + 2 * px_;
  const int zxw = ((px_ >> 4) * 64 + mx + 16 * ((px_ >> 2) & 3)) * 4 + (px_ & 3);

  const uint2* pxp = (const uint2*)Px + (size_t)rr * T_ * 512 + w * 64 + l;

  const int rbase = odd ? 2 : 0;
  const int m0 = q4 * 4 + rbase, m1 = m0 + 1;
  const int pg = w * 8 + (c16 >> 1);
  const int gw0 = ((pg >> 4) * 64 + 16 * ((pg >> 2) & 3)) * 4 + (pg & 3)
                  + 16 * q4 + (odd ? 8 : 0);
  int zw_[2]; size_t hb0_[2], hb1_[2];
#pragma unroll
  for (int ut = 0; ut < 2; ++ut) {
    const int pu = w * 16 + ut * 8 + (c16 >> 1);
    zw_[ut] = ((2 + (pu >> 4)) * 64 + 16 * ((pu >> 2) & 3)) * 4 + (pu & 3)
              + 16 * q4 + (odd ? 8 : 0);
    hb0_[ut] = (size_t)(row0 + m0) * T_ * 128 + pu;
    hb1_[ut] = (size_t)(row0 + m1) * T_ * 128 + pu;
  }

  reinterpret_cast<uint4*>(s_z)[128 + tid] = make_uint4(0u, 0u, 0u, 0u);
  uint2 pxc;
  if (PX) {
    pxc = pxp[0];
  } else {
    __syncthreads();
    float2 xv = *(const float2*)xptr;
    s_z[zxw] = packpair(xv.x, xv.y);
  }
  __syncthreads();

  const uint4* z4 = (const uint4*)s_z;
  const uint4* g4 = (const uint4*)s_g;

  for (int t = 0; t < T_; ++t) {
    uint2 pxn;
    float2 xv;
    const bool more = (t + 1 < T_);
    if (PX) { if (more) pxn = pxp[(size_t)(t + 1) * 512]; }
    else    { if (more) xv = *(const float2*)(xptr + (size_t)(t + 1) * I_); }

    f32x4 aA, aB = {0.f, 0.f, 0.f, 0.f};
    if (PX) {
      aA = (f32x4){unpack_lo(pxc.x), unpack_hi(pxc.x),
                   unpack_lo(pxc.y), unpack_hi(pxc.y)};
      aA = mfma16(z4[2 * 64 + l], wbb[0], aA);
      aB = mfma16(z4[3 * 64 + l], wbb[1], aB);
      aA = mfma16(z4[4 * 64 + l], wbb[2], aA);
      aB = mfma16(z4[5 * 64 + l], wbb[3], aB);
      aA = mfma16(z4[6 * 64 + l], wbb[4], aA);
      aB = mfma16(z4[7 * 64 + l], wbb[5], aB);
      aA = mfma16(z4[8 * 64 + l], wbb[6], aA);
      aB = mfma16(z4[9 * 64 + l], wbb[7], aB);
    } else {
      aA = (f32x4){0.f, 0.f, 0.f, 0.f};
#pragma unroll
      for (int c = 0; c < 10; c += 2) {
        aA = mfma16(z4[c * 64 + l],       wbb[c],     aA);
        aB = mfma16(z4[(c + 1) * 64 + l], wbb[c + 1], aB);
      }
    }
    const f32x4 ab = aA + aB;

    u32 gq[4];
#pragma unroll
    for (int r = 0; r < 4; ++r) {
      const float a  = __builtin_fmaf(ab[r], 1.332f * LOG2E, bgs);
      const float rv = rcpf(exp2fast(a) + 1.0f);
      const float g  = __builtin_fmaf(rv, -3.4318f, 1.7159f);
      const float gp = dpp_mov_f<DPP_XOR1>(g);
      gq[r] = odd ? packpair(gp, g) : packpair(g, gp);
    }
    s_g[gw0]     = odd ? gq[2] : gq[0];
    s_g[gw0 + 4] = odd ? gq[3] : gq[1];
    __syncthreads();

    f32x4 af[3][2];
#pragma unroll
    for (int mt = 0; mt < 3; ++mt)
#pragma unroll
      for (int ut = 0; ut < 2; ++ut)
        af[mt][ut] = (f32x4){0.f, 0.f, 0.f, 0.f};
#pragma unroll
    for (int c = 0; c < 4; ++c) {
      const uint4 ga = g4[c * 64 + l];
#pragma unroll
      for (int mt = 0; mt < 3; ++mt)
#pragma unroll
        for (int ut = 0; ut < 2; ++ut)
          af[mt][ut] = mfma16(ga, wff[mt][ut][c], af[mt][ut]);
    }

#pragma unroll
    for (int ut = 0; ut < 2; ++ut) {
      u32 hq[4];
#pragma unroll
      for (int r = 0; r < 4; ++r) {
        const float E1 = exp2fast(__builtin_fmaf(af[0][ut][r], 2.0f * LOG2E, b1s[ut]));
        const float E2 = exp2fast(__builtin_fmaf(af[1][ut][r], 2.0f * LOG2E, b2s[ut]));
        const float E3 = exp2fast(__builtin_fmaf(af[2][ut][r], -LOG2E, btn[ut]));
        const float p2 = E2 + 1.0f, p3 = E3 + 1.0f;
        const float qq = p2 * p3;
        const float D  = __builtin_fmaf(E1, qq, qq);
        const float R  = rcpf(D);
        const float u2 = (E2 - E1) - qq;
        const float h  = __builtin_fmaf(R + R, u2, 1.0f);
        const float hp = dpp_mov_f<DPP_XOR1>(h);
        hq[r] = odd ? packpair(hp, h) : packpair(h, hp);
      }
      const u32 s0 = odd ? hq[2] : hq[0];
      const u32 s1 = odd ? hq[3] : hq[1];
      s_z[zw_[ut]]     = s0;
      s_z[zw_[ut] + 4] = s1;
      Hbuf[hb0_[ut] + (size_t)t * 128] = s0;
      Hbuf[hb1_[ut] + (size_t)t * 128] = s1;
    }
    if (PX) { pxc = pxn; }
    else    { if (more) s_z[zxw] = packpair(xv.x, xv.y); }
    __syncthreads();
  }

  {
    const uint4 hv = reinterpret_cast<const uint4*>(s_z)[128 + tid];
    float2* tail = (float2*)(out + (size_t)B_ * T_ * O_);
#pragma unroll
    for (int i = 0; i < 4; ++i) {
      const int vh   = tid * 4 + i;
      const int ch   = vh >> 8;
      const int lane = (vh >> 2) & 63;
      const int slot = vh & 3;
      const int m    = lane & 15;
      const int bq   = lane >> 4;
      const int pu   = ch * 16 + bq * 4 + slot;
      const u32 hp   = (i == 0) ? hv.x : (i == 1) ? hv.y : (i == 2) ? hv.z : hv.w;
      float2 hf; hf.x = unpack_lo(hp); hf.y = unpack_hi(hp);
      tail[(size_t)(row0 + m) * 128 + pu] = hf;
    }
  }
}

// ================= fallback (no workspace): dot2 kernel ==========
template <bool DEFER>
__global__ __launch_bounds__(1024)
void cfc_kernel(const float* __restrict__ x,
                const float* __restrict__ W_bb, const float* __restrict__ b_bb,
                const float* __restrict__ W_ff1, const float* __restrict__ b_ff1,
                const float* __restrict__ W_ff2, const float* __restrict__ b_ff2,
                const float* __restrict__ W_ta,  const float* __restrict__ b_ta,
                const float* __restrict__ W_tb,  const float* __restrict__ b_tb,
                const float* __restrict__ W_fc,  const float* __restrict__ b_fc,
                float* __restrict__ out, u32* __restrict__ Hbuf)
{
  __shared__ __align__(16) u32 s_z2[160];
  __shared__ __align__(16) u32 s_g2[64];
  u16* s_gh = (u16*)s_g2;

  const int tid = threadIdx.x;
  const int r   = blockIdx.x;

  const int ca  = tid >> 3;
  const int kga = tid & 7;
  const int jb = tid >> 2;
  const int kq = tid & 3;
  const int ro = tid >> 4;
  const int rk = tid & 15;

  u32 wbb[20];
#pragma unroll
  for (int j = 0; j < 5; ++j)
#pragma unroll
    for (int q = 0; q < 4; ++q) {
      int p = 4 * (kga + 8 * j) + q;
      wbb[4 * j + q] = packpair(W_bb[(2 * p) * BB_ + ca],
                                W_bb[(2 * p + 1) * BB_ + ca]);
    }
  u32 wf1[16], wf2[16], wta[16], wtb[16];
#pragma unroll
  for (int j = 0; j < 4; ++j)
#pragma unroll
    for (int q = 0; q < 4; ++q) {
      int p = 4 * (kq + 4 * j) + q;
      int k0 = 2 * p, k1 = 2 * p + 1;
      wf1[4 * j + q] = packpair(W_ff1[k0 * U_ + jb], W_ff1[k1 * U_ + jb]);
      wf2[4 * j + q] = packpair(W_ff2[k0 * U_ + jb], W_ff2[k1 * U_ + jb]);
      wta[4 * j + q] = packpair(W_ta [k0 * U_ + jb], W_ta [k1 * U_ + jb]);
      wtb[4 * j + q] = packpair(W_tb [k0 * U_ + jb], W_tb [k1 * U_ + jb]);
    }
  u32 wfc[8];
  float bfo = 0.f;
  if (!DEFER) {
#pragma unroll
    for (int j = 0; j < 2; ++j)
#pragma unroll
      for (int q = 0; q < 4; ++q) {
        int p = 4 * (rk + 16 * j) + q;
        wfc[4 * j + q] = packpair(W_fc[(2 * p) * O_ + ro],
                                  W_fc[(2 * p + 1) * O_ + ro]);
      }
    bfo = b_fc[ro];
  }
  const float bbbc = b_bb[ca];
  const float b1 = b_ff1[jb], b2 = b_ff2[jb];
  const float bta = b_ta[jb], btb = b_tb[jb];

  const float* xrow = x + (size_t)r * T_ * I_;
  const size_t out_row = (size_t)r * T_ * O_;
  u32* __restrict__ hrow = DEFER ? (Hbuf + (size_t)r * T_ * (U_ / 2)) : nullptr;

  if (tid < 160) s_z2[tid] = 0u;
  __syncthreads();
  if (tid < 32) {
    float2 xv = ((const float2*)xrow)[tid];
    s_z2[tid] = packpair(xv.x, xv.y);
  }
  __syncthreads();

  for (int t = 0; t < T_; ++t) {
    float2 xv;
    const bool ldx = (tid < 32) && (t + 1 < T_);
    if (ldx) xv = ((const float2*)(xrow + (size_t)(t + 1) * I_))[tid];

    float bacc = 0.f;
#pragma unroll
    for (int j = 0; j < 5; ++j) {
      uint4 zz = *reinterpret_cast<const uint4*>(s_z2 + 4 * (kga + 8 * j));
      bacc = dot2acc(wbb[4 * j + 0], zz.x, bacc);
      bacc = dot2acc(wbb[4 * j + 1], zz.y, bacc);
      bacc = dot2acc(wbb[4 * j + 2], zz.z, bacc);
      bacc = dot2acc(wbb[4 * j + 3], zz.w, bacc);
    }
    bacc += dpp_mov_f<DPP_XOR1>(bacc);
    bacc += dpp_mov_f<DPP_XOR2>(bacc);
    bacc += dpp_mov_f<DPP_HMIR>(bacc);
    float g = 1.7159f * fast_tanh(0.666f * (bacc + bbbc));

    float racc = 0.f;
    if (!DEFER) {
#pragma unroll
      for (int j = 0; j < 2; ++j) {
        uint4 hh = *reinterpret_cast<const uint4*>(s_z2 + 32 + 4 * (rk + 16 * j));
        racc = dot2acc(wfc[4 * j + 0], hh.x, racc);
        racc = dot2acc(wfc[4 * j + 1], hh.y, racc);
        racc = dot2acc(wfc[4 * j + 2], hh.z, racc);
        racc = dot2acc(wfc[4 * j + 3], hh.w, racc);
      }
      racc += dpp_mov_f<DPP_XOR1>(racc);
      racc += dpp_mov_f<DPP_XOR2>(racc);
      racc += dpp_mov_f<DPP_HMIR>(racc);
      racc += dpp_mov_f<DPP_MIRR>(racc);
    }
    if ((tid & 7) == 0)
      s_gh[ca] = __builtin_bit_cast(u16, (_Float16)g);
    if (!DEFER && t > 0 && rk == 0)
      out[out_row + (size_t)(t - 1) * O_ + ro] = racc + bfo;
    __syncthreads();

    float a1 = 0.f, a2 = 0.f, a3 = 0.f, a4 = 0.f;
#pragma unroll
    for (int j = 0; j < 4; ++j) {
      uint4 gg = *reinterpret_cast<const uint4*>(s_g2 + 4 * (kq + 4 * j));
      a1 = dot2acc(wf1[4 * j + 0], gg.x, a1);
      a1 = dot2acc(wf1[4 * j + 1], gg.y, a1);
      a1 = dot2acc(wf1[4 * j + 2], gg.z, a1);
      a1 = dot2acc(wf1[4 * j + 3], gg.w, a1);
      a2 = dot2acc(wf2[4 * j + 0], gg.x, a2);
      a2 = dot2acc(wf2[4 * j + 1], gg.y, a2);
      a2 = dot2acc(wf2[4 * j + 2], gg.z, a2);
      a2 = dot2acc(wf2[4 * j + 3], gg.w, a2);
      a3 = dot2acc(wta[4 * j + 0], gg.x, a3);
      a3 = dot2acc(wta[4 * j + 1], gg.y, a3);
      a3 = dot2acc(wta[4 * j + 2], gg.z, a3);
      a3 = dot2acc(wta[4 * j + 3], gg.w, a3);
      a4 = dot2acc(wtb[4 * j + 0], gg.x, a4);
      a4 = dot2acc(wtb[4 * j + 1], gg.y, a4);
      a4 = dot2acc(wtb[4 * j + 2], gg.z, a4);
      a4 = dot2acc(wtb[4 * j + 3], gg.w, a4);
    }
    a1 += dpp_mov_f<DPP_XOR1>(a1); a1 += dpp_mov_f<DPP_XOR2>(a1);
    a2 += dpp_mov_f<DPP_XOR1>(a2); a2 += dpp_mov_f<DPP_XOR2>(a2);
    a3 += dpp_mov_f<DPP_XOR1>(a3); a3 += dpp_mov_f<DPP_XOR2>(a3);
    a4 += dpp_mov_f<DPP_XOR1>(a4); a4 += dpp_mov_f<DPP_XOR2>(a4);
    float f1 = fast_tanh(a1 + b1);
    float f2 = fast_tanh(a2 + b2);
    float ti = fast_sigmoid(a3 + bta + a4 + btb);
    float h  = f1 + ti * (f2 - f1);
    float hq = dpp_mov_f<DPP_HMIR>(h);

    if ((tid & 7) == 0) {
      u32 pr = packpair(h, hq);
      int m = tid >> 3;
      s_z2[32 + m] = pr;
      if (DEFER) hrow[(size_t)t * (U_ / 2) + m] = pr;
    }
    if (ldx) s_z2[tid] = packpair(xv.x, xv.y);
    __syncthreads();
  }

  if (!DEFER) {
    float racc = 0.f;
#pragma unroll
    for (int j = 0; j < 2; ++j) {
      uint4 hh = *reinterpret_cast<const uint4*>(s_z2 + 32 + 4 * (rk + 16 * j));
      racc = dot2acc(wfc[4 * j + 0], hh.x, racc);
      racc = dot2acc(wfc[4 * j + 1], hh.y, racc);
      racc = dot2acc(wfc[4 * j + 2], hh.z, racc);
      racc = dot2acc(wfc[4 * j + 3], hh.w, racc);
    }
    racc += dpp_mov_f<DPP_XOR1>(racc);
    racc += dpp_mov_f<DPP_XOR2>(racc);
    racc += dpp_mov_f<DPP_HMIR>(racc);
    racc += dpp_mov_f<DPP_MIRR>(racc);
    if (rk == 0)
      out[out_row + (size_t)(T_ - 1) * O_ + ro] = racc + bfo;
  }

  if (tid < 128) {
    u32 hp = s_z2[32 + tid];
    float2 hv; hv.x = unpack_lo(hp); hv.y = unpack_hi(hp);
    ((float2*)(out + (size_t)B_ * T_ * O_))[r * 128 + tid] = hv;
  }
}

// Deferred readout: out[r,t,:] = H[r,t,:] @ W_fc + b_fc.
// NEWPAIR: Hbuf dword pu holds units (32*(pu>>4)+(pu&15), +16).
// old:     Hbuf dword pu holds units (2pu, 2pu+1).
template <bool NEWPAIR>
__global__ __launch_bounds__(512)
void ro_kernel(const u32* __restrict__ Hbuf,
               const float* __restrict__ W_fc, const float* __restrict__ b_fc,
               float* __restrict__ out)
{
  __shared__ __align__(16) u32 s_h[8 * 128];
  const int tid = threadIdx.x;
  const int o   = tid & 63;
  const int w   = tid >> 6;
  const int r   = blockIdx.x;

  u32 wfc[128];
#pragma unroll
  for (int p = 0; p < 128; ++p) {
    if (NEWPAIR) {
      const int ulo = 32 * (p >> 4) + (p & 15);
      wfc[p] = packpair(W_fc[(size_t)ulo * O_ + o],
                        W_fc[(size_t)(ulo + 16) * O_ + o]);
    } else {
      wfc[p] = packpair(W_fc[(2 * p) * O_ + o], W_fc[(2 * p + 1) * O_ + o]);
    }
  }
  const float bo = b_fc[o];

  const u32* hrow = Hbuf + (size_t)r * T_ * 128;
  const size_t out_row = (size_t)r * T_ * O_;

  for (int c = 0; c < T_ / 8; ++c) {
    *(uint2*)(s_h + 2 * tid) =
        *(const uint2*)(hrow + (size_t)c * 1024 + 2 * tid);
    __syncthreads();
    float acc = bo;
    const uint4* h4 = reinterpret_cast<const uint4*>(s_h + w * 128);
#pragma unroll
    for (int i = 0; i < 32; ++i) {
      uint4 hh = h4[i];
      acc = dot2acc(wfc[4 * i + 0], hh.x, acc);
      acc = dot2acc(wfc[4 * i + 1], hh.y, acc);
      acc = dot2acc(wfc[4 * i + 2], hh.z, acc);
      acc = dot2acc(wfc[4 * i + 3], hh.w, acc);
    }
    out[out_row + (size_t)(8 * c + w) * O_ + o] = acc;
    __syncthreads();
  }
}

extern "C" void kernel_launch(void* const* d_in, const int* in_sizes, int n_in,
                              void* d_out, int out_size, void* d_ws, size_t ws_size,
                              hipStream_t stream) {
  const float* x     = (const float*)d_in[0];
  const float* W_bb  = (const float*)d_in[1];
  const float* b_bb  = (const float*)d_in[2];
  const float* W_ff1 = (const float*)d_in[3];
  const float* b_ff1 = (const float*)d_in[4];
  const float* W_ff2 = (const float*)d_in[5];
  const float* b_ff2 = (const float*)d_in[6];
  const float* W_ta  = (const float*)d_in[7];
  const float* b_ta  = (const float*)d_in[8];
  const float* W_tb  = (const float*)d_in[9];
  const float* b_tb  = (const float*)d_in[10];
  const float* W_fc  = (const float*)d_in[11];
  const float* b_fc  = (const float*)d_in[12];
  float* out = (float*)d_out;

  const size_t h_bytes  = (size_t)B_ * T_ * (U_ / 2) * sizeof(u32);  // 128 MiB
  const size_t px_bytes = (size_t)B_ * T_ * (BB_ / 2) * sizeof(u32); //  64 MiB
  if (ws_size >= h_bytes + px_bytes) {
    u32* Hbuf = (u32*)d_ws;
    u32* Px   = (u32*)((char*)d_ws + h_bytes);
    px_kernel<<<dim3(16, T_ / 64), dim3(512), 0, stream>>>(x, W_bb, b_bb, Px);
    cfc_dual<<<dim3(B_ / 32), dim3(512), 0, stream>>>(
        W_bb, W_ff1, b_ff1, W_ff2, b_ff2,
        W_ta, b_ta, W_tb, b_tb, out, Hbuf, Px);
    ro_kernel<true><<<dim3(B_), dim3(512), 0, stream>>>(Hbuf, W_fc, b_fc, out);
  } else if (ws_size >= h_bytes) {
    u32* Hbuf = (u32*)d_ws;
    cfc_mfma<false><<<dim3(B_ / 16), dim3(512), 0, stream>>>(
        x, W_bb, b_bb, W_ff1, b_ff1, W_ff2, b_ff2,
        W_ta, b_ta, W_tb, b_tb, out, Hbuf, nullptr);
    ro_kernel<false><<<dim3(B_), dim3(512), 0, stream>>>(Hbuf, W_fc, b_fc, out);
  } else {
    cfc_kernel<false><<<dim3(B_), dim3(1024), 0, stream>>>(
        x, W_bb, b_bb, W_ff1, b_ff1, W_ff2, b_ff2,
        W_ta, b_ta, W_tb, b_tb, W_fc, b_fc, out, nullptr);
  }
}